// Round 1
// baseline (79.982 us; speedup 1.0000x reference)
//
#include <hip/hip_runtime.h>

#define N        384
#define DIM      256
#define D4       (DIM / 4)       // 64 float4 per row
#define MARGIN_F 0.2f
#define NANCH    2               // anchors per fused block
#define NBLK     (N / NANCH)     // 192 blocks
#define NTHR     384
#define NWAVE    (NTHR / 64)     // 6 waves
#define MAXPOS   64              // labels ~ Binom(384,1/32): mean 12; 64 is >14 sigma

// ---------------------------------------------------------------------------
// Workspace layout (all zero-init done by norm_kernel; no host memset):
//   [0..3]      done_cnt (uint)
//   [16..783]   psum[NBLK]  per-block partial loss sums (distinct slots -> no
//                           same-cacheline atomic serialization)
//   [784..1551] pcnt[NBLK]  per-block partial counts
//   [1552..]    eTv : N*DIM floats as float4[k4][j]  (k4-major, j fastest)
//               -> fused's k-loop load eTv[k4*N + tid] is lane-consecutive 16B
//   then        sqn : N floats, sum(e_norm^2) per row (~1.0; ref recomputes it)
// ---------------------------------------------------------------------------

__global__ __launch_bounds__(64) void norm_kernel(
    const float* __restrict__ emb, float4* __restrict__ eTv,
    float* __restrict__ sqn, float* __restrict__ psum,
    unsigned int* __restrict__ pcnt, unsigned int* __restrict__ done_cnt)
{
    const int row  = blockIdx.x;       // 0..N-1
    const int lane = threadIdx.x;      // 0..63, one float4 each = whole row

    // fold the old 16B memset dispatch into this kernel (stream ordering
    // guarantees these land before fused_kernel starts)
    if (lane == 0) {
        if (row < NBLK) { psum[row] = 0.0f; pcnt[row] = 0u; }
        if (row == 0)   { *done_cnt = 0u; }
    }

    const float4 v = ((const float4*)emb)[row * D4 + lane];   // coalesced 1KB/wave
    float s = v.x*v.x + v.y*v.y + v.z*v.z + v.w*v.w;
    #pragma unroll
    for (int off = 32; off > 0; off >>= 1) s += __shfl_down(s, off, 64);
    const float tot = __shfl(s, 0, 64);                       // broadcast

    const float inv = 1.0f / fmaxf(sqrtf(tot), 1e-12f);
    float4 vn;
    vn.x = v.x * inv; vn.y = v.y * inv; vn.z = v.z * inv; vn.w = v.w * inv;
    eTv[lane * N + row] = vn;          // transposed-float4 store (posted, async)

    if (lane == 0) sqn[row] = tot * inv * inv;   // matches ref's recompute on e_norm
}

__global__ __launch_bounds__(NTHR) void fused_kernel(
    const float4* __restrict__ eTv, const float* __restrict__ sqn,
    const int* __restrict__ labels,
    float* __restrict__ psum, unsigned int* __restrict__ pcnt,
    unsigned int* __restrict__ done_cnt, float* __restrict__ out)
{
    const int i0   = blockIdx.x * NANCH;
    const int tid  = threadIdx.x;      // 0..N-1: one column each
    const int wave = tid >> 6, lane = tid & 63;

    __shared__ float4 ei4[NANCH][D4];  // normalized anchor rows
    __shared__ float  sqa[NANCH];
    __shared__ float  Drow[NANCH][N];  // distance rows (never touch global)
    __shared__ int    lab[N];
    __shared__ int    posList[NANCH][MAXPOS];
    __shared__ int    posCnt[NANCH];
    __shared__ float        sredS[NWAVE];
    __shared__ unsigned int sredC[NWAVE];
    __shared__ int    isLast;

    // stage anchors (already normalized in eTv) + labels
    if (tid < NANCH * D4) {            // 128 threads: a = tid/64, k4 = tid%64
        const int a = tid >> 6, k4 = tid & (D4 - 1);
        ei4[a][k4] = eTv[k4 * N + (i0 + a)];
    }
    if (tid < NANCH) { sqa[tid] = sqn[i0 + tid]; posCnt[tid] = 0; }
    lab[tid] = labels[tid];
    __syncthreads();

    // ---- distance rows: thread tid owns column j = tid; 64 coalesced 16B loads
    float acc0 = 0.0f, acc1 = 0.0f;
    #pragma unroll 16
    for (int k4 = 0; k4 < D4; ++k4) {
        const float4 v  = eTv[k4 * N + tid];   // global_load_dwordx4, 16 in flight
        const float4 a0 = ei4[0][k4];          // ds_read_b128 broadcast (free)
        const float4 a1 = ei4[1][k4];
        acc0 += v.x*a0.x + v.y*a0.y + v.z*a0.z + v.w*a0.w;
        acc1 += v.x*a1.x + v.y*a1.y + v.z*a1.z + v.w*a1.w;
    }
    const float sqj = sqn[tid];
    {
        float d2 = fmaxf(sqa[0] + sqj - 2.0f * acc0, 0.0f);
        Drow[0][tid] = (d2 > 0.0f) ? sqrtf(d2) : 0.0f;   // ref: sqrt(where(pos,d2,1))*pos
        d2       = fmaxf(sqa[1] + sqj - 2.0f * acc1, 0.0f);
        Drow[1][tid] = (d2 > 0.0f) ? sqrtf(d2) : 0.0f;
    }
    __syncthreads();

    // ---- positive lists for both anchors
    const int lj = lab[tid];
    #pragma unroll
    for (int a = 0; a < NANCH; ++a) {
        const int ia = i0 + a;
        if (lj == lab[ia] && tid != ia)
            posList[a][atomicAdd(&posCnt[a], 1)] = tid;
    }
    __syncthreads();

    // ---- semihard accumulation; thread tid owns negative k = tid
    float        lsum = 0.0f;
    unsigned int lcnt = 0u;
    #pragma unroll
    for (int a = 0; a < NANCH; ++a) {
        const int   li = lab[i0 + a];
        const float dk = Drow[a][tid];         // an (if tid is a negative)
        if (lj != li) {
            const int np = posCnt[a];          // ~11 positives
            for (int p = 0; p < np; ++p) {
                const float tm = dk - Drow[a][posList[a][p]];   // an - ap
                if (tm > 0.0f && tm <= MARGIN_F) {
                    const float l = MARGIN_F - tm;              // max(MARGIN-tm,0)
                    lsum += l;
                    if (l > 0.0f) lcnt++;                       // strict losses>0 count
                }
            }
        }
    }

    // ---- block reduce
    #pragma unroll
    for (int off = 32; off > 0; off >>= 1) {
        lsum += __shfl_down(lsum, off, 64);
        lcnt += __shfl_down(lcnt, off, 64);
    }
    if (lane == 0) { sredS[wave] = lsum; sredC[wave] = lcnt; }
    __syncthreads();

    // ---- per-block partial slot (distinct cacheline region per block: no
    //      same-line RMW serialization), then one done atomic per block
    if (tid == 0) {
        float        S = 0.0f;
        unsigned int C = 0u;
        #pragma unroll
        for (int w = 0; w < NWAVE; ++w) { S += sredS[w]; C += sredC[w]; }
        if (S != 0.0f || C != 0u) {
            atomicAdd(&psum[blockIdx.x], S);   // slot pre-zeroed by norm_kernel
            atomicAdd(&pcnt[blockIdx.x], C);
        }
        __threadfence();                        // order slot writes before done++
        const unsigned int prev = atomicAdd(done_cnt, 1);
        isLast = (prev == NBLK - 1) ? 1 : 0;
    }
    __syncthreads();

    // ---- last block: parallel reduce of the 192 slots (atomic reads = coherent
    //      across XCDs), write the mean
    if (isLast) {
        float        s = 0.0f;
        unsigned int c = 0u;
        if (tid < NBLK) {
            s = atomicAdd(&psum[tid], 0.0f);    // atomic read-modify-0: device-coherent
            c = atomicAdd(&pcnt[tid], 0u);
        }
        #pragma unroll
        for (int off = 32; off > 0; off >>= 1) {
            s += __shfl_down(s, off, 64);
            c += __shfl_down(c, off, 64);
        }
        if (lane == 0) { sredS[wave] = s; sredC[wave] = c; }
        __syncthreads();
        if (tid == 0) {
            float        Sall = 0.0f;
            unsigned int Call = 0u;
            #pragma unroll
            for (int w = 0; w < NWAVE; ++w) { Sall += sredS[w]; Call += sredC[w]; }
            out[0] = (Call > 0u) ? (Sall / (float)Call) : 0.0f;
        }
    }
}

extern "C" void kernel_launch(void* const* d_in, const int* in_sizes, int n_in,
                              void* d_out, int out_size, void* d_ws, size_t ws_size,
                              hipStream_t stream) {
    const float* emb    = (const float*)d_in[0];   // (384, 256) fp32
    const int*   labels = (const int*)d_in[1];     // (384,) int32
    float*       out    = (float*)d_out;           // scalar fp32

    unsigned int* done_cnt = (unsigned int*)d_ws;                          // [0..3]
    float*        psum     = (float*)((char*)d_ws + 16);                   // 192 f32
    unsigned int* pcnt     = (unsigned int*)((char*)d_ws + 16 + 768);      // 192 u32
    float4*       eTv      = (float4*)((char*)d_ws + 1552);                // N*DIM f32
    float*        sqn      = (float*)((char*)d_ws + 1552 + (size_t)N * DIM * 4);

    // no memset dispatch: norm_kernel zeroes done_cnt + partial slots
    norm_kernel<<<N, 64, 0, stream>>>(emb, eTv, sqn, psum, pcnt, done_cnt);
    fused_kernel<<<NBLK, NTHR, 0, stream>>>(eTv, sqn, labels,
                                            psum, pcnt, done_cnt, out);
}